// Round 2
// baseline (423.298 us; speedup 1.0000x reference)
//
#include <hip/hip_runtime.h>
#include <math.h>

#define N_NODES 100000
#define N_FEAT  512
#define HIDDEN  128
#define N_CLASS 16
#define N_EDGES 3200000
#define ALPHA   0.25f

#define NB   782          // ceil(100000/128) buckets of 128 src nodes
#define CAP  5120         // fixed bucket window (mean 4096, sigma 64 -> +16 sigma)
#define TILE 8192         // edges per partition block
#define NTB  391          // ceil(N_EDGES / TILE)

typedef __attribute__((ext_vector_type(8))) short short8;
typedef __attribute__((ext_vector_type(4))) float float4v;
typedef __attribute__((ext_vector_type(4))) unsigned uint4v;
typedef __attribute__((ext_vector_type(4))) int int4v;

__device__ inline short f2b(float f) {
    union { float f; unsigned u; } c; c.f = f;
    unsigned r = c.u + 0x7FFF + ((c.u >> 16) & 1);   // round-to-nearest-even
    return (short)(r >> 16);
}

// async global->LDS, 16B per lane; LDS dest is wave-uniform base + lane*16
__device__ __forceinline__ void async_copy16(void* l, const void* g) {
    __builtin_amdgcn_global_load_lds(
        (const __attribute__((address_space(1))) void*)g,
        (__attribute__((address_space(3))) void*)l, 16, 0, 0);
}

// ---------------------------------------------------------------------------
// prep: bf16-transpose W1/W2 + init bucket cursors (no memset needed)
// ---------------------------------------------------------------------------
__global__ void prep_kernel(const float* __restrict__ W1, const float* __restrict__ W2,
                            short* __restrict__ W1t, short* __restrict__ W2t,
                            int* __restrict__ cursor) {
    int t = blockIdx.x * 256 + threadIdx.x;
    if (t < N_FEAT * HIDDEN) {                 // t = n*512 + k
        int k = t & 511, n = t >> 9;
        W1t[t] = f2b(W1[(size_t)k * HIDDEN + n]);
    }
    int t2 = t - N_FEAT * HIDDEN;
    if (t2 >= 0 && t2 < HIDDEN * N_CLASS) {    // t2 = n*128 + k
        int k = t2 & 127, n = t2 >> 7;
        W2t[t2] = f2b(W2[(size_t)k * N_CLASS + n]);
    }
    if (t < NB) cursor[t] = t * CAP;
}

// ---------------------------------------------------------------------------
// Fused MLP via MFMA: local = relu(x@W1)@W2, bf16 inputs / fp32 accum.
// x staged fp32 via global_load_lds; W1t staged bf16 via global_load_lds.
// Source-side XOR swizzle kills ds_read bank conflicts.
// LDS: union(Asf 16K + Bt 8K, Hs 34.8K) + W2ts 4.3K = 39.2 KB -> 4 blk/CU.
// ---------------------------------------------------------------------------
__global__ __launch_bounds__(256) void mlp_mfma(const float* __restrict__ x,
                                                const short* __restrict__ W1t,
                                                const short* __restrict__ W2t,
                                                float* __restrict__ local_out,
                                                unsigned short* __restrict__ Lbf) {
    __shared__ __align__(16) char uS[34816];          // Asf[128][32]f32 | Bt[128][32]bf16 ; later Hs[128][136]bf16
    __shared__ __align__(16) short W2ts[16 * 136];

    float* const Asf = (float*)uS;                    // 16384 B
    short* const Bt  = (short*)(uS + 16384);          // 8192 B
    short* const Hs  = (short*)uS;                    // 34816 B (after k-loop)

    const int tid  = threadIdx.x;
    const int wave = tid >> 6;
    const int wl   = tid & 63;
    const int lane15 = wl & 15;
    const int quad   = wl >> 4;
    const long block_row = (long)blockIdx.x * 128;

    {
        int n = tid >> 4, koff = (tid & 15) * 8;
        *(short8*)&W2ts[n * 136 + koff] = *(const short8*)&W2t[n * 128 + koff];
    }

    float4v acc[4][4];
#pragma unroll
    for (int i = 0; i < 4; ++i)
#pragma unroll
        for (int j = 0; j < 4; ++j) acc[i][j] = (float4v){0.f, 0.f, 0.f, 0.f};

    const int wr0 = (wave >> 1) * 64;
    const int wc0 = (wave & 1) * 64;

    // per-thread staging constants
    const int a_rsub = wl >> 3;                        // 0..7 (row within 8-row chunk)
    const int a_cch  = (wl & 7) ^ a_rsub;              // swizzled 16B col-chunk 0..7
    const int b_rsub = wl >> 2;                        // 0..15
    const int b_cch  = (wl & 3) ^ ((wl >> 3) & 3);     // swizzled 16B col-chunk 0..3
    char* const aBase = uS + wave * 4096;
    char* const bBase = uS + 16384 + wave * 2048;

    const int r7 = lane15 & 7;
    const int rb = (lane15 >> 1) & 3;

    for (int k0 = 0; k0 < N_FEAT; k0 += 32) {
        // --- stage A (fp32 x) : wave w covers rows w*32..w*32+31, 4 calls x 1KB
#pragma unroll
        for (int c = 0; c < 4; ++c) {
            long gr = block_row + wave * 32 + c * 8 + a_rsub;
            if (gr > N_NODES - 1) gr = N_NODES - 1;    // clamp: dup row, rows >=N discarded
            async_copy16(aBase + c * 1024, x + gr * N_FEAT + k0 + a_cch * 4);
        }
        // --- stage B (bf16 W1t) : 2 calls x 1KB
#pragma unroll
        for (int c = 0; c < 2; ++c) {
            int rr = wave * 32 + c * 16 + b_rsub;
            async_copy16(bBase + c * 1024, W1t + rr * 512 + k0 + b_cch * 8);
        }
        __syncthreads();   // drains vmcnt -> staged data visible to all waves

        short8 af[4], bfr[4];
#pragma unroll
        for (int i = 0; i < 4; ++i) {
            const float* pa = Asf + (wr0 + i * 16 + lane15) * 32;
            float4 va = *(const float4*)(pa + (((2 * quad) ^ r7) << 2));
            float4 vb = *(const float4*)(pa + (((2 * quad + 1) ^ r7) << 2));
            short8 h;
            h[0] = f2b(va.x); h[1] = f2b(va.y); h[2] = f2b(va.z); h[3] = f2b(va.w);
            h[4] = f2b(vb.x); h[5] = f2b(vb.y); h[6] = f2b(vb.z); h[7] = f2b(vb.w);
            af[i] = h;
        }
#pragma unroll
        for (int j = 0; j < 4; ++j) {
            const short* pb = Bt + (wc0 + j * 16 + lane15) * 32;
            bfr[j] = *(const short8*)(pb + ((quad ^ rb) << 3));
        }
#pragma unroll
        for (int i = 0; i < 4; ++i)
#pragma unroll
            for (int j = 0; j < 4; ++j)
                acc[i][j] = __builtin_amdgcn_mfma_f32_16x16x32_bf16(af[i], bfr[j], acc[i][j], 0, 0, 0);
        __syncthreads();   // all reads done before next stage overwrites
    }

    // Hs overlays Asf/Bt (dead after final barrier above)
#pragma unroll
    for (int i = 0; i < 4; ++i)
#pragma unroll
        for (int j = 0; j < 4; ++j)
#pragma unroll
            for (int r = 0; r < 4; ++r) {
                int row = wr0 + i * 16 + quad * 4 + r;
                int colh = wc0 + j * 16 + lane15;
                Hs[row * 136 + colh] = f2b(fmaxf(acc[i][j][r], 0.f));
            }
    __syncthreads();

    float4v acc2[2];
    acc2[0] = (float4v){0.f, 0.f, 0.f, 0.f};
    acc2[1] = acc2[0];
#pragma unroll
    for (int ks = 0; ks < 4; ++ks) {
        short8 a0 = *(short8*)&Hs[(wave * 32 + lane15) * 136 + ks * 32 + quad * 8];
        short8 a1 = *(short8*)&Hs[(wave * 32 + 16 + lane15) * 136 + ks * 32 + quad * 8];
        short8 b  = *(short8*)&W2ts[lane15 * 136 + ks * 32 + quad * 8];
        acc2[0] = __builtin_amdgcn_mfma_f32_16x16x32_bf16(a0, b, acc2[0], 0, 0, 0);
        acc2[1] = __builtin_amdgcn_mfma_f32_16x16x32_bf16(a1, b, acc2[1], 0, 0, 0);
    }
#pragma unroll
    for (int i2 = 0; i2 < 2; ++i2)
#pragma unroll
        for (int r = 0; r < 4; ++r) {
            long grow = block_row + wave * 32 + i2 * 16 + quad * 4 + r;
            if (grow < N_NODES) {
                float v = acc2[i2][r];
                local_out[grow * N_CLASS + lane15] = v;
                Lbf[grow * N_CLASS + lane15] = (unsigned short)f2b(v);
            }
        }
}

// ---------------------------------------------------------------------------
// partition: LDS rank + reorder + coalesced flush into fixed b*CAP windows.
// src/dst read as nt int4 (pure stream, 4x fewer VMEM instrs; edge order
// within a bucket is already nondeterministic via atomics, so reorder is
// semantics-preserving). bbuf written nt (single-use until next kernel).
// ---------------------------------------------------------------------------
__global__ __launch_bounds__(256) void partition_kernel(const int* __restrict__ src,
                                                        const int* __restrict__ dst,
                                                        int* __restrict__ cursor,
                                                        unsigned* __restrict__ bbuf) {
    __shared__ unsigned sbuf[TILE];
    __shared__ unsigned short sbkt[TILE];
    __shared__ int cnt[1024];
    __shared__ int off[1024];
    __shared__ int gbase[NB];
    __shared__ int psum[256];

    const int tid = threadIdx.x;
    const int e0 = blockIdx.x * TILE;
    int n = N_EDGES - e0; if (n > TILE) n = TILE;   // n % 4 == 0 always (8192 or 5120)

    for (int i = tid; i < 1024; i += 256) cnt[i] = 0;
    __syncthreads();

    unsigned pk[32]; int br[32];
#pragma unroll
    for (int k = 0; k < 8; ++k) {
        int i0 = k * 1024 + tid * 4;
        if (i0 < n) {
            int4v s4 = __builtin_nontemporal_load((const int4v*)&src[e0 + i0]);
            int4v d4 = __builtin_nontemporal_load((const int4v*)&dst[e0 + i0]);
#pragma unroll
            for (int j = 0; j < 4; ++j) {
                int s = s4[j], d = d4[j];
                int b = s >> 7;
                int r = atomicAdd(&cnt[b], 1);
                pk[k * 4 + j] = ((unsigned)(s & 127) << 17) | (unsigned)d;
                br[k * 4 + j] = (b << 13) | r;
            }
        } else {
#pragma unroll
            for (int j = 0; j < 4; ++j) br[k * 4 + j] = -1;
        }
    }
    __syncthreads();

    int b4 = tid * 4;
    int c0 = cnt[b4], c1 = cnt[b4 + 1], c2 = cnt[b4 + 2], c3 = cnt[b4 + 3];
    int tsum = c0 + c1 + c2 + c3;
    psum[tid] = tsum;
    __syncthreads();
    for (int o = 1; o < 256; o <<= 1) {
        int t = (tid >= o) ? psum[tid - o] : 0;
        __syncthreads();
        psum[tid] += t;
        __syncthreads();
    }
    int run = psum[tid] - tsum;
    off[b4] = run; off[b4 + 1] = run + c0;
    off[b4 + 2] = run + c0 + c1; off[b4 + 3] = run + c0 + c1 + c2;
    __syncthreads();

    for (int b = tid; b < NB; b += 256) {
        int c = cnt[b];
        if (c > 0) gbase[b] = atomicAdd(&cursor[b], c);
    }

#pragma unroll
    for (int k = 0; k < 32; ++k) {
        if (br[k] >= 0) {
            int b = br[k] >> 13, r = br[k] & 8191;
            int slot = off[b] + r;
            sbuf[slot] = pk[k];
            sbkt[slot] = (unsigned short)b;
        }
    }
    __syncthreads();

    for (int i = tid; i < n; i += 256) {
        int b = sbkt[i];
        __builtin_nontemporal_store(sbuf[i], &bbuf[gbase[b] + (i - off[b])]);
    }
}

// ---------------------------------------------------------------------------
// bucket_sort: one block per bucket. Sort bucket's edges by src slot in LDS
// (hist + scan + rank), write back node-contiguous dst list (in place) and
// exact row_start / row_end / scale. bbuf traffic marked nt (single-use).
// ---------------------------------------------------------------------------
__global__ __launch_bounds__(512) void bucket_sort(unsigned* __restrict__ bbuf,
                                                   const int* __restrict__ cursor,
                                                   int* __restrict__ row_start,
                                                   int* __restrict__ row_end,
                                                   float* __restrict__ scale) {
    __shared__ unsigned ein[CAP];      // 20 KB
    __shared__ unsigned eout[CAP];     // 20 KB
    __shared__ int cnt[128], ssc[128], cur[128];

    const int b = blockIdx.x;
    const int tid = threadIdx.x;
    const int base = b * CAP;
    int n = cursor[b] - base; if (n > CAP) n = CAP;

    for (int i = tid; i < n; i += 512) ein[i] = __builtin_nontemporal_load(&bbuf[base + i]);
    if (tid < 128) cnt[tid] = 0;
    __syncthreads();

    for (int i = tid; i < n; i += 512) atomicAdd(&cnt[ein[i] >> 17], 1);
    __syncthreads();

    int v = (tid < 128) ? cnt[tid] : 0;
    if (tid < 128) ssc[tid] = v;
    __syncthreads();
    for (int o = 1; o < 128; o <<= 1) {
        int t = (tid >= o && tid < 128) ? ssc[tid - o] : 0;
        __syncthreads();
        if (tid < 128) ssc[tid] += t;
        __syncthreads();
    }
    if (tid < 128) cur[tid] = ssc[tid] - v;   // exclusive prefix
    __syncthreads();

    for (int i = tid; i < n; i += 512) {
        unsigned u = ein[i];
        int r = atomicAdd(&cur[u >> 17], 1);
        eout[r] = u & 0x1FFFFu;
    }
    __syncthreads();

    for (int i = tid; i < n; i += 512) __builtin_nontemporal_store(eout[i], &bbuf[base + i]);

    if (tid < 128) {
        int node = (b << 7) + tid;
        if (node < N_NODES) {
            int st = base + ssc[tid] - v;
            row_start[node] = st;
            row_end[node]   = st + v;
            scale[node] = (1.0f - ALPHA) / fmaxf((float)v, 1e-12f);
        }
    }
}

// ---------------------------------------------------------------------------
// spmm_csr: 2 lanes per node; lane gathers 16B (8 bf16 classes) per edge with
// 16 edges in flight. CACHE POLICY: col / local / outputs are single-use
// streams -> nontemporal (evict-first), so the heavily-reused gather table
// Ltab (3.2MB, ~4 reuses per line per XCD) stays resident in the 4MB L2.
// PASS 1 -> bf16 out; PASS 2 -> fused log_softmax, fp32 out.
// ---------------------------------------------------------------------------
template <int PASS>
__global__ __launch_bounds__(512) void spmm_csr(const unsigned* __restrict__ col,
                                                const int* __restrict__ row_start,
                                                const int* __restrict__ row_end,
                                                const float* __restrict__ scale,
                                                const unsigned short* __restrict__ Ltab,
                                                const float* __restrict__ local,
                                                unsigned short* __restrict__ out_bf,
                                                float* __restrict__ out_f32) {
    int t = blockIdx.x * 512 + threadIdx.x;
    int node = t >> 1;
    int half = t & 1;
    if (node >= N_NODES) return;
    const int rs = row_start[node], re = row_end[node];

    float acc[8];
#pragma unroll
    for (int k = 0; k < 8; ++k) acc[k] = 0.f;

    for (int base = rs & ~3; base < re; base += 16) {
        // 4 aligned 16B nt col loads (bbuf is 64B-aligned; base % 4 == 0)
        const uint4v q0 = __builtin_nontemporal_load((const uint4v*)&col[base]);
        const uint4v q1 = __builtin_nontemporal_load((const uint4v*)&col[base + 4]);
        const uint4v q2 = __builtin_nontemporal_load((const uint4v*)&col[base + 8]);
        const uint4v q3 = __builtin_nontemporal_load((const uint4v*)&col[base + 12]);
        int cc[16];
        cc[0]  = (int)q0[0]; cc[1]  = (int)q0[1]; cc[2]  = (int)q0[2]; cc[3]  = (int)q0[3];
        cc[4]  = (int)q1[0]; cc[5]  = (int)q1[1]; cc[6]  = (int)q1[2]; cc[7]  = (int)q1[3];
        cc[8]  = (int)q2[0]; cc[9]  = (int)q2[1]; cc[10] = (int)q2[2]; cc[11] = (int)q2[3];
        cc[12] = (int)q3[0]; cc[13] = (int)q3[1]; cc[14] = (int)q3[2]; cc[15] = (int)q3[3];
#pragma unroll
        for (int j = 0; j < 16; ++j) {
            int idx = base + j;
            if (idx < rs || idx >= re) cc[j] = -1;
        }
        uint4 g[16];
#pragma unroll
        for (int j = 0; j < 16; ++j) {
            int c = (cc[j] < 0) ? 0 : cc[j];
            g[j] = *(const uint4*)&Ltab[(size_t)c * N_CLASS + half * 8];   // cached (reused)
        }
#pragma unroll
        for (int j = 0; j < 16; ++j) {
            if (cc[j] >= 0) {
                union { unsigned u; float f; } w;
                w.u = g[j].x << 16;          acc[0] += w.f;
                w.u = g[j].x & 0xFFFF0000u;  acc[1] += w.f;
                w.u = g[j].y << 16;          acc[2] += w.f;
                w.u = g[j].y & 0xFFFF0000u;  acc[3] += w.f;
                w.u = g[j].z << 16;          acc[4] += w.f;
                w.u = g[j].z & 0xFFFF0000u;  acc[5] += w.f;
                w.u = g[j].w << 16;          acc[6] += w.f;
                w.u = g[j].w & 0xFFFF0000u;  acc[7] += w.f;
            }
        }
    }

    const float sc = scale[node];
    const float* lp = &local[(size_t)node * N_CLASS + half * 8];
    float4v l0 = __builtin_nontemporal_load((const float4v*)lp);
    float4v l1 = __builtin_nontemporal_load((const float4v*)(lp + 4));
    float r[8];
    r[0] = sc * acc[0] + ALPHA * l0[0]; r[1] = sc * acc[1] + ALPHA * l0[1];
    r[2] = sc * acc[2] + ALPHA * l0[2]; r[3] = sc * acc[3] + ALPHA * l0[3];
    r[4] = sc * acc[4] + ALPHA * l1[0]; r[5] = sc * acc[5] + ALPHA * l1[1];
    r[6] = sc * acc[6] + ALPHA * l1[2]; r[7] = sc * acc[7] + ALPHA * l1[3];

    if (PASS == 1) {
        uint4v o;
        o[0] = ((unsigned)(unsigned short)f2b(r[1]) << 16) | (unsigned)(unsigned short)f2b(r[0]);
        o[1] = ((unsigned)(unsigned short)f2b(r[3]) << 16) | (unsigned)(unsigned short)f2b(r[2]);
        o[2] = ((unsigned)(unsigned short)f2b(r[5]) << 16) | (unsigned)(unsigned short)f2b(r[4]);
        o[3] = ((unsigned)(unsigned short)f2b(r[7]) << 16) | (unsigned)(unsigned short)f2b(r[6]);
        __builtin_nontemporal_store(o, (uint4v*)&out_bf[(size_t)node * N_CLASS + half * 8]);
    } else {
        float mx = r[0];
#pragma unroll
        for (int k = 1; k < 8; ++k) mx = fmaxf(mx, r[k]);
        mx = fmaxf(mx, __shfl_xor(mx, 1));
        float sm = 0.f;
#pragma unroll
        for (int k = 0; k < 8; ++k) sm += expf(r[k] - mx);
        sm += __shfl_xor(sm, 1);
        float ls = logf(sm) + mx;
        float4v o0 = {r[0] - ls, r[1] - ls, r[2] - ls, r[3] - ls};
        float4v o1 = {r[4] - ls, r[5] - ls, r[6] - ls, r[7] - ls};
        float* op = &out_f32[(size_t)node * N_CLASS + half * 8];
        __builtin_nontemporal_store(o0, (float4v*)op);
        __builtin_nontemporal_store(o1, (float4v*)(op + 4));
    }
}

// ---------------------------------------------------------------------------
extern "C" void kernel_launch(void* const* d_in, const int* in_sizes, int n_in,
                              void* d_out, int out_size, void* d_ws, size_t ws_size,
                              hipStream_t stream) {
    const float* x    = (const float*)d_in[0];
    const float* W1   = (const float*)d_in[1];
    const float* W2   = (const float*)d_in[2];
    const int*   esrc = (const int*)d_in[3];
    const int*   edst = (const int*)d_in[4];
    float* out = (float*)d_out;
    char*  ws  = (char*)d_ws;

    // workspace layout (bytes) — bbuf 64B-aligned for uint4 col loads
    float*          local   = (float*)         (ws + 0);          //  6,400,000
    unsigned short* Lbf     = (unsigned short*)(ws + 6400000);    //  3,200,000
    unsigned short* P1bf    = (unsigned short*)(ws + 9600000);    //  3,200,000
    float*          scale   = (float*)         (ws + 12800000);   //    400,000
    int*            rstart  = (int*)           (ws + 13200000);   //    400,000
    int*            rend    = (int*)           (ws + 13600000);   //    400,000
    short*          W1t     = (short*)         (ws + 14000000);   //    131,072
    short*          W2t     = (short*)         (ws + 14131072);   //      4,096
    int*            cursor  = (int*)           (ws + 14135168);   //      3,128
    unsigned*       bbuf    = (unsigned*)      (ws + 14138368);   // 16,015,360 +64 pad (end ~30.2 MB)

    prep_kernel<<<(N_FEAT * HIDDEN + HIDDEN * N_CLASS + 255) / 256, 256, 0, stream>>>(W1, W2, W1t, W2t, cursor);
    mlp_mfma<<<(N_NODES + 127) / 128, 256, 0, stream>>>(x, W1t, W2t, local, Lbf);

    partition_kernel<<<NTB, 256, 0, stream>>>(esrc, edst, cursor, bbuf);
    bucket_sort<<<NB, 512, 0, stream>>>(bbuf, cursor, rstart, rend, scale);

    const int sgrid = (N_NODES * 2 + 511) / 512;
    spmm_csr<1><<<sgrid, 512, 0, stream>>>(bbuf, rstart, rend, scale, Lbf,  local, P1bf, nullptr);
    spmm_csr<2><<<sgrid, 512, 0, stream>>>(bbuf, rstart, rend, scale, P1bf, local, nullptr, out);
}

// Round 3
// 397.228 us; speedup vs baseline: 1.0656x; 1.0656x over previous
//
#include <hip/hip_runtime.h>
#include <math.h>

#define N_NODES 100000
#define N_FEAT  512
#define HIDDEN  128
#define N_CLASS 16
#define N_EDGES 3200000
#define ALPHA   0.25f

#define NB   782          // ceil(100000/128) buckets of 128 src nodes
#define CAP  5120         // fixed bucket window (mean 4096, sigma 64 -> +16 sigma)
#define TILE 8192         // edges per partition block
#define NTB  391          // ceil(N_EDGES / TILE)

typedef __attribute__((ext_vector_type(8))) short short8;
typedef __attribute__((ext_vector_type(4))) float float4v;
typedef __attribute__((ext_vector_type(4))) unsigned uint4v;
typedef __attribute__((ext_vector_type(4))) int int4v;

__device__ inline short f2b(float f) {
    union { float f; unsigned u; } c; c.f = f;
    unsigned r = c.u + 0x7FFF + ((c.u >> 16) & 1);   // round-to-nearest-even
    return (short)(r >> 16);
}

// async global->LDS, 16B per lane; LDS dest is wave-uniform base + lane*16
__device__ __forceinline__ void async_copy16(void* l, const void* g) {
    __builtin_amdgcn_global_load_lds(
        (const __attribute__((address_space(1))) void*)g,
        (__attribute__((address_space(3))) void*)l, 16, 0, 0);
}

// ---------------------------------------------------------------------------
// prep: bf16-transpose W1/W2 + init bucket cursors (no memset needed)
// ---------------------------------------------------------------------------
__global__ void prep_kernel(const float* __restrict__ W1, const float* __restrict__ W2,
                            short* __restrict__ W1t, short* __restrict__ W2t,
                            int* __restrict__ cursor) {
    int t = blockIdx.x * 256 + threadIdx.x;
    if (t < N_FEAT * HIDDEN) {                 // t = n*512 + k
        int k = t & 511, n = t >> 9;
        W1t[t] = f2b(W1[(size_t)k * HIDDEN + n]);
    }
    int t2 = t - N_FEAT * HIDDEN;
    if (t2 >= 0 && t2 < HIDDEN * N_CLASS) {    // t2 = n*128 + k
        int k = t2 & 127, n = t2 >> 7;
        W2t[t2] = f2b(W2[(size_t)k * N_CLASS + n]);
    }
    if (t < NB) cursor[t] = t * CAP;
}

// ---------------------------------------------------------------------------
// Fused MLP via MFMA: local = relu(x@W1)@W2, bf16 inputs / fp32 accum.
// x staged fp32 via global_load_lds; W1t staged bf16 via global_load_lds.
// Source-side XOR swizzle kills ds_read bank conflicts.
// ---------------------------------------------------------------------------
__global__ __launch_bounds__(256) void mlp_mfma(const float* __restrict__ x,
                                                const short* __restrict__ W1t,
                                                const short* __restrict__ W2t,
                                                float* __restrict__ local_out,
                                                unsigned short* __restrict__ Lbf) {
    __shared__ __align__(16) char uS[34816];          // Asf[128][32]f32 | Bt[128][32]bf16 ; later Hs[128][136]bf16
    __shared__ __align__(16) short W2ts[16 * 136];

    float* const Asf = (float*)uS;                    // 16384 B
    short* const Bt  = (short*)(uS + 16384);          // 8192 B
    short* const Hs  = (short*)uS;                    // 34816 B (after k-loop)

    const int tid  = threadIdx.x;
    const int wave = tid >> 6;
    const int wl   = tid & 63;
    const int lane15 = wl & 15;
    const int quad   = wl >> 4;
    const long block_row = (long)blockIdx.x * 128;

    {
        int n = tid >> 4, koff = (tid & 15) * 8;
        *(short8*)&W2ts[n * 136 + koff] = *(const short8*)&W2t[n * 128 + koff];
    }

    float4v acc[4][4];
#pragma unroll
    for (int i = 0; i < 4; ++i)
#pragma unroll
        for (int j = 0; j < 4; ++j) acc[i][j] = (float4v){0.f, 0.f, 0.f, 0.f};

    const int wr0 = (wave >> 1) * 64;
    const int wc0 = (wave & 1) * 64;

    const int a_rsub = wl >> 3;                        // 0..7
    const int a_cch  = (wl & 7) ^ a_rsub;              // swizzled 16B col-chunk 0..7
    const int b_rsub = wl >> 2;                        // 0..15
    const int b_cch  = (wl & 3) ^ ((wl >> 3) & 3);     // swizzled 16B col-chunk 0..3
    char* const aBase = uS + wave * 4096;
    char* const bBase = uS + 16384 + wave * 2048;

    const int r7 = lane15 & 7;
    const int rb = (lane15 >> 1) & 3;

    for (int k0 = 0; k0 < N_FEAT; k0 += 32) {
#pragma unroll
        for (int c = 0; c < 4; ++c) {
            long gr = block_row + wave * 32 + c * 8 + a_rsub;
            if (gr > N_NODES - 1) gr = N_NODES - 1;
            async_copy16(aBase + c * 1024, x + gr * N_FEAT + k0 + a_cch * 4);
        }
#pragma unroll
        for (int c = 0; c < 2; ++c) {
            int rr = wave * 32 + c * 16 + b_rsub;
            async_copy16(bBase + c * 1024, W1t + rr * 512 + k0 + b_cch * 8);
        }
        __syncthreads();

        short8 af[4], bfr[4];
#pragma unroll
        for (int i = 0; i < 4; ++i) {
            const float* pa = Asf + (wr0 + i * 16 + lane15) * 32;
            float4 va = *(const float4*)(pa + (((2 * quad) ^ r7) << 2));
            float4 vb = *(const float4*)(pa + (((2 * quad + 1) ^ r7) << 2));
            short8 h;
            h[0] = f2b(va.x); h[1] = f2b(va.y); h[2] = f2b(va.z); h[3] = f2b(va.w);
            h[4] = f2b(vb.x); h[5] = f2b(vb.y); h[6] = f2b(vb.z); h[7] = f2b(vb.w);
            af[i] = h;
        }
#pragma unroll
        for (int j = 0; j < 4; ++j) {
            const short* pb = Bt + (wc0 + j * 16 + lane15) * 32;
            bfr[j] = *(const short8*)(pb + ((quad ^ rb) << 3));
        }
#pragma unroll
        for (int i = 0; i < 4; ++i)
#pragma unroll
            for (int j = 0; j < 4; ++j)
                acc[i][j] = __builtin_amdgcn_mfma_f32_16x16x32_bf16(af[i], bfr[j], acc[i][j], 0, 0, 0);
        __syncthreads();
    }

#pragma unroll
    for (int i = 0; i < 4; ++i)
#pragma unroll
        for (int j = 0; j < 4; ++j)
#pragma unroll
            for (int r = 0; r < 4; ++r) {
                int row = wr0 + i * 16 + quad * 4 + r;
                int colh = wc0 + j * 16 + lane15;
                Hs[row * 136 + colh] = f2b(fmaxf(acc[i][j][r], 0.f));
            }
    __syncthreads();

    float4v acc2[2];
    acc2[0] = (float4v){0.f, 0.f, 0.f, 0.f};
    acc2[1] = acc2[0];
#pragma unroll
    for (int ks = 0; ks < 4; ++ks) {
        short8 a0 = *(short8*)&Hs[(wave * 32 + lane15) * 136 + ks * 32 + quad * 8];
        short8 a1 = *(short8*)&Hs[(wave * 32 + 16 + lane15) * 136 + ks * 32 + quad * 8];
        short8 b  = *(short8*)&W2ts[lane15 * 136 + ks * 32 + quad * 8];
        acc2[0] = __builtin_amdgcn_mfma_f32_16x16x32_bf16(a0, b, acc2[0], 0, 0, 0);
        acc2[1] = __builtin_amdgcn_mfma_f32_16x16x32_bf16(a1, b, acc2[1], 0, 0, 0);
    }
#pragma unroll
    for (int i2 = 0; i2 < 2; ++i2)
#pragma unroll
        for (int r = 0; r < 4; ++r) {
            long grow = block_row + wave * 32 + i2 * 16 + quad * 4 + r;
            if (grow < N_NODES) {
                float v = acc2[i2][r];
                local_out[grow * N_CLASS + lane15] = v;
                Lbf[grow * N_CLASS + lane15] = (unsigned short)f2b(v);
            }
        }
}

// ---------------------------------------------------------------------------
// partition: LDS rank + reorder + coalesced flush into fixed b*CAP windows.
// nt LOADS on the src/dst stream only; bbuf stores stay CACHED (bucket kernel
// re-reads them immediately — nt stores here were the R2 mistake).
// ---------------------------------------------------------------------------
__global__ __launch_bounds__(256) void partition_kernel(const int* __restrict__ src,
                                                        const int* __restrict__ dst,
                                                        int* __restrict__ cursor,
                                                        unsigned* __restrict__ bbuf) {
    __shared__ unsigned sbuf[TILE];
    __shared__ unsigned short sbkt[TILE];
    __shared__ int cnt[1024];
    __shared__ int off[1024];
    __shared__ int gbase[NB];
    __shared__ int psum[256];

    const int tid = threadIdx.x;
    const int e0 = blockIdx.x * TILE;
    int n = N_EDGES - e0; if (n > TILE) n = TILE;   // n % 4 == 0 always

    for (int i = tid; i < 1024; i += 256) cnt[i] = 0;
    __syncthreads();

    unsigned pk[32]; int br[32];
#pragma unroll
    for (int k = 0; k < 8; ++k) {
        int i0 = k * 1024 + tid * 4;
        if (i0 < n) {
            int4v s4 = __builtin_nontemporal_load((const int4v*)&src[e0 + i0]);
            int4v d4 = __builtin_nontemporal_load((const int4v*)&dst[e0 + i0]);
#pragma unroll
            for (int j = 0; j < 4; ++j) {
                int s = s4[j], d = d4[j];
                int b = s >> 7;
                int r = atomicAdd(&cnt[b], 1);
                pk[k * 4 + j] = ((unsigned)(s & 127) << 17) | (unsigned)d;
                br[k * 4 + j] = (b << 13) | r;
            }
        } else {
#pragma unroll
            for (int j = 0; j < 4; ++j) br[k * 4 + j] = -1;
        }
    }
    __syncthreads();

    int b4 = tid * 4;
    int c0 = cnt[b4], c1 = cnt[b4 + 1], c2 = cnt[b4 + 2], c3 = cnt[b4 + 3];
    int tsum = c0 + c1 + c2 + c3;
    psum[tid] = tsum;
    __syncthreads();
    for (int o = 1; o < 256; o <<= 1) {
        int t = (tid >= o) ? psum[tid - o] : 0;
        __syncthreads();
        psum[tid] += t;
        __syncthreads();
    }
    int run = psum[tid] - tsum;
    off[b4] = run; off[b4 + 1] = run + c0;
    off[b4 + 2] = run + c0 + c1; off[b4 + 3] = run + c0 + c1 + c2;
    __syncthreads();

    for (int b = tid; b < NB; b += 256) {
        int c = cnt[b];
        if (c > 0) gbase[b] = atomicAdd(&cursor[b], c);
    }

#pragma unroll
    for (int k = 0; k < 32; ++k) {
        if (br[k] >= 0) {
            int b = br[k] >> 13, r = br[k] & 8191;
            int slot = off[b] + r;
            sbuf[slot] = pk[k];
            sbkt[slot] = (unsigned short)b;
        }
    }
    __syncthreads();

    for (int i = tid; i < n; i += 256) {
        int b = sbkt[i];
        bbuf[gbase[b] + (i - off[b])] = sbuf[i];          // cached store
    }
}

// ---------------------------------------------------------------------------
// bucket_sort_spmm: one block per bucket. (a) sort bucket's edges by src slot
// in LDS (hist + scan + rank), write node-contiguous dst list back (for pass
// 2) + row meta. (b) FUSED spmm pass 1 straight from the sorted LDS list:
// 4 lanes per node (2 edge-parities x 2 class-halves), register accumulation,
// shfl parity-combine, bf16 P1 written (cached — it is pass 2's gather table).
// ---------------------------------------------------------------------------
__global__ __launch_bounds__(512) void bucket_sort_spmm(unsigned* __restrict__ bbuf,
                                                        const int* __restrict__ cursor,
                                                        int* __restrict__ row_start,
                                                        int* __restrict__ row_end,
                                                        float* __restrict__ scale,
                                                        const unsigned short* __restrict__ Ltab,
                                                        const float* __restrict__ local,
                                                        unsigned short* __restrict__ P1bf) {
    __shared__ unsigned ein[CAP];      // 20 KB
    __shared__ unsigned eout[CAP];     // 20 KB
    __shared__ int cnt[128], ssc[128], cur[128];

    const int b = blockIdx.x;
    const int tid = threadIdx.x;
    const int base = b * CAP;
    int n = cursor[b] - base; if (n > CAP) n = CAP;

    for (int i = tid; i < n; i += 512) ein[i] = __builtin_nontemporal_load(&bbuf[base + i]);
    if (tid < 128) cnt[tid] = 0;
    __syncthreads();

    for (int i = tid; i < n; i += 512) atomicAdd(&cnt[ein[i] >> 17], 1);
    __syncthreads();

    int v = (tid < 128) ? cnt[tid] : 0;
    if (tid < 128) ssc[tid] = v;
    __syncthreads();
    for (int o = 1; o < 128; o <<= 1) {
        int t = (tid >= o && tid < 128) ? ssc[tid - o] : 0;
        __syncthreads();
        if (tid < 128) ssc[tid] += t;
        __syncthreads();
    }
    if (tid < 128) cur[tid] = ssc[tid] - v;   // exclusive prefix
    __syncthreads();

    for (int i = tid; i < n; i += 512) {
        unsigned u = ein[i];
        int r = atomicAdd(&cur[u >> 17], 1);
        eout[r] = u & 0x1FFFFu;               // dst only (17 bits)
    }
    __syncthreads();

    // write back sorted list for pass 2 (cached) + row meta
    for (int i = tid; i < n; i += 512) bbuf[base + i] = eout[i];
    if (tid < 128) {
        int node = (b << 7) + tid;
        if (node < N_NODES) {
            int st = base + ssc[tid] - v;
            row_start[node] = st;
            row_end[node]   = st + v;
            scale[node] = (1.0f - ALPHA) / fmaxf((float)v, 1e-12f);
        }
    }

    // ---- fused spmm pass 1 on this bucket (reads eout/cnt/ssc, all stable) ----
    const int slot = tid >> 2;           // 0..127
    const int sub  = tid & 3;
    const int half = sub & 1;            // which 8 classes (16B)
    const int par  = sub >> 1;           // edge parity
    const int node = (b << 7) + slot;
    const int re_l = ssc[slot];
    const int rs_l = re_l - cnt[slot];

    float acc[8];
#pragma unroll
    for (int k = 0; k < 8; ++k) acc[k] = 0.f;

    for (int b0 = rs_l; b0 < re_l; b0 += 16) {
        int cc[8];
#pragma unroll
        for (int j = 0; j < 8; ++j) {
            int e = b0 + 2 * j + par;
            cc[j] = (e < re_l) ? (int)eout[e] : -1;
        }
        uint4 g[8];
#pragma unroll
        for (int j = 0; j < 8; ++j) {
            int c = (cc[j] < 0) ? 0 : cc[j];
            g[j] = *(const uint4*)&Ltab[(size_t)c * N_CLASS + half * 8];
        }
#pragma unroll
        for (int j = 0; j < 8; ++j) {
            if (cc[j] >= 0) {
                union { unsigned u; float f; } w;
                w.u = g[j].x << 16;          acc[0] += w.f;
                w.u = g[j].x & 0xFFFF0000u;  acc[1] += w.f;
                w.u = g[j].y << 16;          acc[2] += w.f;
                w.u = g[j].y & 0xFFFF0000u;  acc[3] += w.f;
                w.u = g[j].z << 16;          acc[4] += w.f;
                w.u = g[j].z & 0xFFFF0000u;  acc[5] += w.f;
                w.u = g[j].w << 16;          acc[6] += w.f;
                w.u = g[j].w & 0xFFFF0000u;  acc[7] += w.f;
            }
        }
    }
#pragma unroll
    for (int k = 0; k < 8; ++k) acc[k] += __shfl_xor(acc[k], 2);   // combine parities

    if (par == 0 && node < N_NODES) {
        const float sc = (1.0f - ALPHA) / fmaxf((float)cnt[slot], 1e-12f);
        const float* lp = &local[(size_t)node * N_CLASS + half * 8];
        float4v l0 = __builtin_nontemporal_load((const float4v*)lp);
        float4v l1 = __builtin_nontemporal_load((const float4v*)(lp + 4));
        float r[8];
        r[0] = sc * acc[0] + ALPHA * l0[0]; r[1] = sc * acc[1] + ALPHA * l0[1];
        r[2] = sc * acc[2] + ALPHA * l0[2]; r[3] = sc * acc[3] + ALPHA * l0[3];
        r[4] = sc * acc[4] + ALPHA * l1[0]; r[5] = sc * acc[5] + ALPHA * l1[1];
        r[6] = sc * acc[6] + ALPHA * l1[2]; r[7] = sc * acc[7] + ALPHA * l1[3];
        uint4v o;
        o[0] = ((unsigned)(unsigned short)f2b(r[1]) << 16) | (unsigned)(unsigned short)f2b(r[0]);
        o[1] = ((unsigned)(unsigned short)f2b(r[3]) << 16) | (unsigned)(unsigned short)f2b(r[2]);
        o[2] = ((unsigned)(unsigned short)f2b(r[5]) << 16) | (unsigned)(unsigned short)f2b(r[4]);
        o[3] = ((unsigned)(unsigned short)f2b(r[7]) << 16) | (unsigned)(unsigned short)f2b(r[6]);
        *(uint4v*)&P1bf[(size_t)node * N_CLASS + half * 8] = o;    // cached store
    }
}

// ---------------------------------------------------------------------------
// spmm pass 2: 4 lanes per node (2 edge-parities x 2 class-halves) — halves
// the dependent-gather chain per lane and doubles wave-level parallelism;
// batch=8 keeps g[] at 32 VGPR for higher occupancy. Fused log_softmax.
// ---------------------------------------------------------------------------
__global__ __launch_bounds__(512) void spmm_pass2(const unsigned* __restrict__ col,
                                                  const int* __restrict__ row_start,
                                                  const int* __restrict__ row_end,
                                                  const float* __restrict__ scale,
                                                  const unsigned short* __restrict__ Ltab,
                                                  const float* __restrict__ local,
                                                  float* __restrict__ out_f32) {
    int t = blockIdx.x * 512 + threadIdx.x;
    int node = t >> 2;
    if (node >= N_NODES) return;
    const int sub  = t & 3;
    const int half = sub & 1;
    const int par  = sub >> 1;
    const int rs = row_start[node], re = row_end[node];

    float acc[8];
#pragma unroll
    for (int k = 0; k < 8; ++k) acc[k] = 0.f;

    for (int b0 = rs & ~3; b0 < re; b0 += 16) {
        const uint4v q0 = __builtin_nontemporal_load((const uint4v*)&col[b0]);
        const uint4v q1 = __builtin_nontemporal_load((const uint4v*)&col[b0 + 4]);
        const uint4v q2 = __builtin_nontemporal_load((const uint4v*)&col[b0 + 8]);
        const uint4v q3 = __builtin_nontemporal_load((const uint4v*)&col[b0 + 12]);
        unsigned ce[8];
        ce[0] = par ? q0[1] : q0[0];  ce[1] = par ? q0[3] : q0[2];
        ce[2] = par ? q1[1] : q1[0];  ce[3] = par ? q1[3] : q1[2];
        ce[4] = par ? q2[1] : q2[0];  ce[5] = par ? q2[3] : q2[2];
        int cc[8];
        unsigned ce6 = par ? q3[1] : q3[0], ce7 = par ? q3[3] : q3[2];
        ce[6] = ce6; ce[7] = ce7;
#pragma unroll
        for (int j = 0; j < 8; ++j) {
            int e = b0 + 2 * j + par;
            cc[j] = (e >= rs && e < re) ? (int)ce[j] : -1;
        }
        uint4 g[8];
#pragma unroll
        for (int j = 0; j < 8; ++j) {
            int c = (cc[j] < 0) ? 0 : cc[j];
            g[j] = *(const uint4*)&Ltab[(size_t)c * N_CLASS + half * 8];   // cached (reused)
        }
#pragma unroll
        for (int j = 0; j < 8; ++j) {
            if (cc[j] >= 0) {
                union { unsigned u; float f; } w;
                w.u = g[j].x << 16;          acc[0] += w.f;
                w.u = g[j].x & 0xFFFF0000u;  acc[1] += w.f;
                w.u = g[j].y << 16;          acc[2] += w.f;
                w.u = g[j].y & 0xFFFF0000u;  acc[3] += w.f;
                w.u = g[j].z << 16;          acc[4] += w.f;
                w.u = g[j].z & 0xFFFF0000u;  acc[5] += w.f;
                w.u = g[j].w << 16;          acc[6] += w.f;
                w.u = g[j].w & 0xFFFF0000u;  acc[7] += w.f;
            }
        }
    }
#pragma unroll
    for (int k = 0; k < 8; ++k) acc[k] += __shfl_xor(acc[k], 2);   // combine parities

    if (par == 0) {
        const float sc = scale[node];
        const float* lp = &local[(size_t)node * N_CLASS + half * 8];
        float4v l0 = __builtin_nontemporal_load((const float4v*)lp);
        float4v l1 = __builtin_nontemporal_load((const float4v*)(lp + 4));
        float r[8];
        r[0] = sc * acc[0] + ALPHA * l0[0]; r[1] = sc * acc[1] + ALPHA * l0[1];
        r[2] = sc * acc[2] + ALPHA * l0[2]; r[3] = sc * acc[3] + ALPHA * l0[3];
        r[4] = sc * acc[4] + ALPHA * l1[0]; r[5] = sc * acc[5] + ALPHA * l1[1];
        r[6] = sc * acc[6] + ALPHA * l1[2]; r[7] = sc * acc[7] + ALPHA * l1[3];

        float mx = r[0];
#pragma unroll
        for (int k = 1; k < 8; ++k) mx = fmaxf(mx, r[k]);
        mx = fmaxf(mx, __shfl_xor(mx, 1));                         // combine halves
        float sm = 0.f;
#pragma unroll
        for (int k = 0; k < 8; ++k) sm += expf(r[k] - mx);
        sm += __shfl_xor(sm, 1);
        float ls = logf(sm) + mx;
        float4v o0 = {r[0] - ls, r[1] - ls, r[2] - ls, r[3] - ls};
        float4v o1 = {r[4] - ls, r[5] - ls, r[6] - ls, r[7] - ls};
        float* op = &out_f32[(size_t)node * N_CLASS + half * 8];
        __builtin_nontemporal_store(o0, (float4v*)op);
        __builtin_nontemporal_store(o1, (float4v*)(op + 4));
    }
}

// ---------------------------------------------------------------------------
extern "C" void kernel_launch(void* const* d_in, const int* in_sizes, int n_in,
                              void* d_out, int out_size, void* d_ws, size_t ws_size,
                              hipStream_t stream) {
    const float* x    = (const float*)d_in[0];
    const float* W1   = (const float*)d_in[1];
    const float* W2   = (const float*)d_in[2];
    const int*   esrc = (const int*)d_in[3];
    const int*   edst = (const int*)d_in[4];
    float* out = (float*)d_out;
    char*  ws  = (char*)d_ws;

    // workspace layout (bytes) — bbuf 64B-aligned for uint4 col loads
    float*          local   = (float*)         (ws + 0);          //  6,400,000
    unsigned short* Lbf     = (unsigned short*)(ws + 6400000);    //  3,200,000
    unsigned short* P1bf    = (unsigned short*)(ws + 9600000);    //  3,200,000
    float*          scale   = (float*)         (ws + 12800000);   //    400,000
    int*            rstart  = (int*)           (ws + 13200000);   //    400,000
    int*            rend    = (int*)           (ws + 13600000);   //    400,000
    short*          W1t     = (short*)         (ws + 14000000);   //    131,072
    short*          W2t     = (short*)         (ws + 14131072);   //      4,096
    int*            cursor  = (int*)           (ws + 14135168);   //      3,128
    unsigned*       bbuf    = (unsigned*)      (ws + 14138368);   // 16,015,360 +64 pad

    prep_kernel<<<(N_FEAT * HIDDEN + HIDDEN * N_CLASS + 255) / 256, 256, 0, stream>>>(W1, W2, W1t, W2t, cursor);
    mlp_mfma<<<(N_NODES + 127) / 128, 256, 0, stream>>>(x, W1t, W2t, local, Lbf);

    partition_kernel<<<NTB, 256, 0, stream>>>(esrc, edst, cursor, bbuf);
    bucket_sort_spmm<<<NB, 512, 0, stream>>>(bbuf, cursor, rstart, rend, scale, Lbf, local, P1bf);

    const int p2grid = (N_NODES * 4 + 511) / 512;
    spmm_pass2<<<p2grid, 512, 0, stream>>>(bbuf, rstart, rend, scale, P1bf, local, out);
}